// Round 1
// baseline (3086.573 us; speedup 1.0000x reference)
//
#include <hip/hip_runtime.h>

#define B_   64
#define T_   4096
#define HID_ 128

typedef float f32x4 __attribute__((ext_vector_type(4)));
typedef short s16x8 __attribute__((ext_vector_type(8)));
typedef short s16x4 __attribute__((ext_vector_type(4)));

__device__ __forceinline__ float fexp2(float x){ float r; asm("v_exp_f32 %0, %1":"=v"(r):"v"(x)); return r; }
__device__ __forceinline__ float frcp (float x){ float r; asm("v_rcp_f32 %0, %1":"=v"(r):"v"(x)); return r; }
__device__ __forceinline__ unsigned short f2bf(float f){
    unsigned u = __float_as_uint(f);
    u += 0x7FFFu + ((u >> 16) & 1u);      // round-to-nearest-even
    return (unsigned short)(u >> 16);
}
__device__ __forceinline__ float sigf(float x){
    return frcp(1.0f + fexp2(-1.44269504089f * x));
}

// ---------------- Phase 1: ODE features -> feats[B][T][32] bf16 ----------------
__global__ __launch_bounds__(256) void k_feats(
    const float* __restrict__ x, const float* __restrict__ u,
    const float* __restrict__ dtp, const float* __restrict__ theta,
    const float* __restrict__ He, const float* __restrict__ taue,
    const float* __restrict__ Hi, const float* __restrict__ taui,
    const float* __restrict__ l1, const float* __restrict__ l2,
    const float* __restrict__ l3, const float* __restrict__ l4,
    const float* __restrict__ Cf, const float* __restrict__ Cl,
    const float* __restrict__ Cu, const float* __restrict__ Cb,
    unsigned short* __restrict__ feats)
{
    long idx = (long)blockIdx.x * 256 + threadIdx.x;   // b*T + t
    const float dt = dtp[0];
    const float th00 = theta[0], th01 = theta[1], th10 = theta[2], th11 = theta[3];
    const float he = He[0], te = taue[0], hi = Hi[0], ti = taui[0];
    const float L1 = l1[0], L2v = l2[0], L3 = l3[0], L4 = l4[0];
    float cf[4], cl[4], cu[4], cb[4];
    #pragma unroll
    for (int i = 0; i < 4; ++i){ cf[i]=Cf[i]; cl[i]=Cl[i]; cu[i]=Cu[i]; cb[i]=Cb[i]; }
    const float ite  = 1.f/te, iti = 1.f/ti;
    const float He_te = he*ite, ite2 = ite*ite;
    const float Hi_ti = hi*iti, iti2 = iti*iti;

    float X[22];
    const float2* xr = (const float2*)(x + idx*22);
    #pragma unroll
    for (int i = 0; i < 11; ++i){ float2 v = xr[i]; X[2*i] = v.x; X[2*i+1] = v.y; }
    float2 uv = ((const float2*)u)[idx];

    float xt0 = X[0]*th00 + X[1]*th10;     // x[...,0,:] @ theta  ('btn,nm')
    float xt1 = X[0]*th01 + X[1]*th11;
    float ut0 = uv.x*th00 + uv.y*th10;
    float ut1 = uv.x*th01 + uv.y*th11;
    float s0 = sigf(xt0), s1 = sigf(xt1);

    // 'btn,mn->btm' : out[m] = sum_n M[m][n]*v[n]
    float Mf00 = cf[0]+cl[0]+L1, Mf01 = cf[1]+cl[1], Mf10 = cf[2]+cl[2], Mf11 = cf[3]+cl[3]+L1;
    float Af0 = Mf00*s0 + Mf01*s1, Af1 = Mf10*s0 + Mf11*s1;
    float Au0 = cu[0]*ut0 + cu[1]*ut1, Au1 = cu[2]*ut0 + cu[3]*ut1;
    float Mb00 = cb[0]+cl[0], Mb01 = cb[1]+cl[1], Mb10 = cb[2]+cl[2], Mb11 = cb[3]+cl[3];
    float Abl0 = Mb00*s0 + Mb01*s1, Abl1 = Mb10*s0 + Mb11*s1;
    float A30 = (Mb00+L3)*s0 + Mb01*s1,  A31 = Mb10*s0 + (Mb11+L3)*s1;

    float F[22];
    F[0]  = X[0]  + dt*(X[10]-X[12]);
    F[1]  = X[1]  + dt*(X[11]-X[13]);
    F[2]  = X[2]  + dt*X[8];
    F[3]  = X[3]  + dt*X[9];
    F[4]  = X[4]  + dt*X[10];
    F[5]  = X[5]  + dt*X[11];
    F[6]  = X[6]  + dt*X[12];
    F[7]  = X[7]  + dt*X[13];
    F[8]  = X[8]  + dt*(He_te*(Af0+Au0) - 2.f*X[8]*ite  - X[2]*ite2);
    F[9]  = X[9]  + dt*(He_te*(Af1+Au1) - 2.f*X[9]*ite  - X[3]*ite2);
    F[10] = X[10] + dt*(He_te*(Abl0 + L2v*sigf(X[6])) - 2.f*X[10]*ite - X[4]*ite2);
    F[11] = X[11] + dt*(He_te*(Abl1 + L2v*sigf(X[7])) - 2.f*X[11]*ite - X[5]*ite2);
    F[12] = X[12] + dt*(Hi_ti*L4*sigf(X[14]) - 2.f*X[12]*iti - X[6]*iti2);
    F[13] = X[13] + dt*(Hi_ti*L4*sigf(X[15]) - 2.f*X[13]*iti - X[7]*iti2);
    F[14] = X[14] + dt*X[16];
    F[15] = X[15] + dt*X[17];
    F[16] = X[16] + dt*(He_te*A30 - 2.f*X[16]*ite - X[14]*ite2);
    F[17] = X[17] + dt*(He_te*A31 - 2.f*X[17]*ite - X[15]*ite2);
    F[18] = X[18]; F[19] = X[19]; F[20] = X[20]; F[21] = X[21];

    unsigned short o[32];
    #pragma unroll
    for (int i = 0; i < 22; ++i) o[i] = f2bf(F[i]);
    #pragma unroll
    for (int i = 22; i < 32; ++i) o[i] = 0;
    uint4* dst = (uint4*)(feats + idx*32);
    #pragma unroll
    for (int q = 0; q < 4; ++q){
        uint4 v;
        v.x = (unsigned)o[q*8+0] | ((unsigned)o[q*8+1] << 16);
        v.y = (unsigned)o[q*8+2] | ((unsigned)o[q*8+3] << 16);
        v.z = (unsigned)o[q*8+4] | ((unsigned)o[q*8+5] << 16);
        v.w = (unsigned)o[q*8+6] | ((unsigned)o[q*8+7] << 16);
        dst[q] = v;
    }
}

// ---------------- Phase 2: LSTM scan + fused W_lin head ----------------
// 16 blocks x 4 batches. 512 threads = 8 waves; wave w owns j in [w*16, w*16+16).
// Batch b sits at MFMA A-row 4b -> every lane's D reg0 holds one (b,j) gate value.
// LDS tile row = A-row (16 rows, stride 168 bf16 = 336B): cols [0,32) feats_t, [32,160) h_{t-1}.
__global__ __launch_bounds__(512, 2) void k_scan(
    const unsigned short* __restrict__ feats,
    const float* __restrict__ Wih, const float* __restrict__ Whh,
    const float* __restrict__ bih, const float* __restrict__ bhh,
    const float* __restrict__ Wlin, const float* __restrict__ blin,
    float* __restrict__ out)
{
    __shared__ __align__(16) unsigned short lbuf[2][16*168];
    __shared__ __align__(16) float ypart[2][4][2][8];   // [parity][b][o][wave]

    const int tid = threadIdx.x;
    const int w  = tid >> 6;
    const int l  = tid & 63;
    const int lm = l & 15;          // A/D column-lane (M-row for A, N-col for D)
    const int lg = l >> 4;          // lane group -> batch (via spread rows 4b)
    const int gb0 = blockIdx.x * 4;

    // zero LDS (pad rows must stay zero forever)
    {
        unsigned* p = (unsigned*)&lbuf[0][0];
        for (int i = tid; i < 2*16*168/2; i += 512) p[i] = 0u;
        float* yp = (float*)&ypart[0][0][0][0];
        if (tid < 128) yp[tid] = 0.f;
    }

    // ---- pack weight B-fragments into registers (bf16) ----
    const int nj = w*16 + lm;       // this thread's hidden index j
    s16x8 bw[4][5];
    #pragma unroll
    for (int t4 = 0; t4 < 4; ++t4){
        int n = t4*128 + nj;        // gate row: i,f,g,o blocks of 128
        #pragma unroll
        for (int kc = 0; kc < 5; ++kc){
            #pragma unroll
            for (int j = 0; j < 8; ++j){
                int k = kc*32 + lg*4 + (j & 3) + ((j >> 2) << 4);
                float wv = 0.f;
                if (kc == 0){ if (k < 22) wv = Wih[n*22 + k]; }
                else        { wv = Whh[n*128 + (k - 32)]; }
                bw[t4][kc][j] = (short)f2bf(wv);
            }
        }
    }
    const float L2E = 1.44269504089f;
    float nLb0, nLb1, nLb3, b2g;
    {
        float bi = bih[0*128+nj] + bhh[0*128+nj];
        float bf = bih[1*128+nj] + bhh[1*128+nj];
        float bg = bih[2*128+nj] + bhh[2*128+nj];
        float bo = bih[3*128+nj] + bhh[3*128+nj];
        nLb0 = -L2E*bi; nLb1 = -L2E*bf; nLb3 = -L2E*bo; b2g = 2.f*L2E*bg;
    }
    const float wl0 = Wlin[nj], wl1 = Wlin[128+nj];
    const float bl = (l < 8) ? blin[l & 1] : 0.f;

    __syncthreads();   // zeroing visible

    // preload feats(t=0) into buf0; pending = feats(t=1)
    uint4 pending = {0,0,0,0};
    if (w == 4 && l < 16){
        int fb = l >> 2, fc = l & 3;
        const char* srcb = (const char*)feats + ((long)(gb0+fb)*T_)*64;
        uint4 f0 = *(const uint4*)(srcb + fc*16);
        *(uint4*)((char*)&lbuf[0][0] + (4*fb)*336 + fc*16) = f0;
        pending = *(const uint4*)(srcb + 64 + fc*16);
    }
    __syncthreads();

    const int a_base = lm*336 + lg*8;   // byte offset of this lane's A-frag in a buffer
    float c = 0.f;

    for (int t = 0; t < T_; ++t){
        const int cur = t & 1, nxt = cur ^ 1;
        const char* bp = (const char*)&lbuf[cur][0];

        // A fragments: row lm, k = kc*32 + lg*4 + {0..3} (+16 for hi half)
        s16x8 af[5];
        #pragma unroll
        for (int kc = 0; kc < 5; ++kc){
            s16x4 lo = *(const s16x4*)(bp + a_base + kc*64);
            s16x4 hi = *(const s16x4*)(bp + a_base + kc*64 + 32);
            af[kc] = (s16x8){lo[0],lo[1],lo[2],lo[3],hi[0],hi[1],hi[2],hi[3]};
        }
        f32x4 ac0 = {0,0,0,0}, ac1 = {0,0,0,0}, ac2 = {0,0,0,0}, ac3 = {0,0,0,0};
        #pragma unroll
        for (int kc = 0; kc < 5; ++kc){
            ac0 = __builtin_amdgcn_mfma_f32_16x16x32_bf16(af[kc], bw[0][kc], ac0, 0,0,0);
            ac1 = __builtin_amdgcn_mfma_f32_16x16x32_bf16(af[kc], bw[1][kc], ac1, 0,0,0);
            ac2 = __builtin_amdgcn_mfma_f32_16x16x32_bf16(af[kc], bw[2][kc], ac2, 0,0,0);
            ac3 = __builtin_amdgcn_mfma_f32_16x16x32_bf16(af[kc], bw[3][kc], ac3, 0,0,0);
        }

        // wave 4: stage feats(t+1) into buf[nxt], prefetch feats(t+2)
        if (w == 4 && l < 16){
            int fb = l >> 2, fc = l & 3;
            *(uint4*)((char*)&lbuf[nxt][0] + (4*fb)*336 + fc*16) = pending;
            int tn = (t+2 < T_) ? t+2 : T_-1;
            pending = *(const uint4*)((const char*)feats + ((long)(gb0+fb)*T_ + tn)*64 + fc*16);
        }
        // wave 5: finish y(t-1) = sum_w ypart + b_lin, store
        if (w == 5 && l < 8 && t > 0){
            int b = l >> 1, o = l & 1;
            const float* yp = &ypart[nxt][b][o][0];          // (t-1)&1 == nxt
            f32x4 p0 = *(const f32x4*)yp, p1 = *(const f32x4*)(yp+4);
            out[((long)(gb0+b)*T_ + (t-1))*2 + o] =
                ((p0[0]+p0[1])+(p0[2]+p0[3])) + ((p1[0]+p1[1])+(p1[2]+p1[3])) + bl;
        }

        // activations: this thread's (b,j) = (lg, nj); gate pre-acts in reg0
        float si = frcp(1.f + fexp2(fmaf(ac0[0], -L2E, nLb0)));
        float sf = frcp(1.f + fexp2(fmaf(ac1[0], -L2E, nLb1)));
        float so = frcp(1.f + fexp2(fmaf(ac3[0], -L2E, nLb3)));
        float eg = fexp2(fmaf(ac2[0], 2.f*L2E, b2g));
        float tg = fmaf(-2.f, frcp(1.f + eg), 1.f);
        c = sf*c + si*tg;
        float ec = fexp2(c * (2.f*L2E));
        float tc = fmaf(-2.f, frcp(1.f + ec), 1.f);
        float h = so * tc;

        // write h (bf16) for next step: row 4b, col 32+j
        ((unsigned short*)&lbuf[nxt][0])[(4*lg)*168 + 32 + nj] = f2bf(h);

        // y partials: reduce over this wave's 16 j's (lanes lm within group lg)
        float y0 = h*wl0, y1 = h*wl1;
        #pragma unroll
        for (int m = 1; m < 16; m <<= 1){ y0 += __shfl_xor(y0, m); y1 += __shfl_xor(y1, m); }
        if (lm == 0){ ypart[cur][lg][0][w] = y0; ypart[cur][lg][1][w] = y1; }

        __syncthreads();
    }
    // epilogue: y(T-1), parity (T-1)&1 == 1
    if (w == 5 && l < 8){
        int b = l >> 1, o = l & 1;
        const float* yp = &ypart[1][b][o][0];
        f32x4 p0 = *(const f32x4*)yp, p1 = *(const f32x4*)(yp+4);
        out[((long)(gb0+b)*T_ + (T_-1))*2 + o] =
            ((p0[0]+p0[1])+(p0[2]+p0[3])) + ((p1[0]+p1[1])+(p1[2]+p1[3])) + bl;
    }
}

extern "C" void kernel_launch(void* const* d_in, const int* in_sizes, int n_in,
                              void* d_out, int out_size, void* d_ws, size_t ws_size,
                              hipStream_t stream)
{
    const float* x     = (const float*)d_in[0];
    const float* u     = (const float*)d_in[1];
    const float* dtp   = (const float*)d_in[2];
    const float* theta = (const float*)d_in[3];
    const float* He    = (const float*)d_in[4];
    const float* taue  = (const float*)d_in[5];
    const float* Hi    = (const float*)d_in[6];
    const float* taui  = (const float*)d_in[7];
    const float* l1    = (const float*)d_in[8];
    const float* l2    = (const float*)d_in[9];
    const float* l3    = (const float*)d_in[10];
    const float* l4    = (const float*)d_in[11];
    const float* Cf    = (const float*)d_in[12];
    const float* Cl    = (const float*)d_in[13];
    const float* Cu    = (const float*)d_in[14];
    const float* Cb    = (const float*)d_in[15];
    const float* Wih   = (const float*)d_in[16];
    const float* Whh   = (const float*)d_in[17];
    const float* bih   = (const float*)d_in[18];
    const float* bhh   = (const float*)d_in[19];
    const float* Wlin  = (const float*)d_in[20];
    const float* blin  = (const float*)d_in[21];

    unsigned short* feats = (unsigned short*)d_ws;   // B*T*32 bf16 = 16 MiB

    k_feats<<<(B_*T_)/256, 256, 0, stream>>>(x,u,dtp,theta,He,taue,Hi,taui,
                                             l1,l2,l3,l4,Cf,Cl,Cu,Cb,feats);
    k_scan<<<16, 512, 0, stream>>>(feats, Wih, Whh, bih, bhh, Wlin, blin, (float*)d_out);
}